// Round 1
// baseline (189.409 us; speedup 1.0000x reference)
//
#include <hip/hip_runtime.h>

#define NG 100   // graph size
#define DD 128   // feature dim

// LDS layout (floats):
//   [0, 6400)      xsT[dl][n] = x[n][64*h + dl], dl in [0,64), n in [0,100)
//   [6400, 6800)   red_max[4][100]  per-wave partial column max
//   [6800, 7200)   red_sum[4][100]  per-wave partial column sum
#define REDMAX 6400
#define REDSUM 6800
#define SMSZ   7200

// One block per batch graph. 256 threads = 4 waves.
// Lane owns output columns m = 2*lane, 2*lane+1  (valid for lane < 50).
// Wave owns row-tiles nt = wave + 4*i  (4 rows each; nt<25; wave0 gets 7 tiles, others 6).
__global__ __launch_bounds__(256, 4)
void dotdec_kernel(const float* __restrict__ x, float* __restrict__ out) {
    __shared__ float sm[SMSZ];
    const int t    = threadIdx.x;
    const int lane = t & 63;
    const int wave = t >> 6;
    const int b    = blockIdx.x;
    const float* xb = x   + (size_t)b * (NG * DD);
    float*       ob = out + (size_t)b * (NG * NG);

    // acc[i][j][r]: row n = 4*(wave+4*i)+j, col m = 2*lane+r
    float acc[7][4][2];
#pragma unroll
    for (int i = 0; i < 7; ++i)
#pragma unroll
        for (int j = 0; j < 4; ++j) { acc[i][j][0] = 0.f; acc[i][j][1] = 0.f; }

    for (int h = 0; h < 2; ++h) {
        if (h) __syncthreads();   // previous half's GEMM reads done before overwrite
        // stage transposed d-half into LDS: 1600 float4 loads, coalesced
#pragma unroll
        for (int k = 0; k < 7; ++k) {
            int i4 = t + 256 * k;
            if (i4 < 1600) {
                int n  = i4 >> 4;         // row
                int dq = i4 & 15;         // float4 within the 64-float half-row
                float4 v = ((const float4*)xb)[n * 32 + h * 16 + dq];
                int dl = dq * 4;
                sm[(dl + 0) * NG + n] = v.x;   // lane-stride 400 words = 16 mod 32 banks: 2-way, free
                sm[(dl + 1) * NG + n] = v.y;
                sm[(dl + 2) * NG + n] = v.z;
                sm[(dl + 3) * NG + n] = v.w;
            }
        }
        __syncthreads();

        for (int dl = 0; dl < 64; ++dl) {
            const float* row = &sm[dl * NG];
            // lane's two columns: consecutive floats, conflict-free b64
            float2 mv = *(const float2*)&row[2 * lane];
#pragma unroll
            for (int i = 0; i < 6; ++i) {
                int nt = wave + 4 * i;
                float4 nv = *(const float4*)&row[4 * nt];  // wave-uniform -> LDS broadcast
                acc[i][0][0] += nv.x * mv.x; acc[i][0][1] += nv.x * mv.y;
                acc[i][1][0] += nv.y * mv.x; acc[i][1][1] += nv.y * mv.y;
                acc[i][2][0] += nv.z * mv.x; acc[i][2][1] += nv.z * mv.y;
                acc[i][3][0] += nv.w * mv.x; acc[i][3][1] += nv.w * mv.y;
            }
            if (wave == 0) {               // tile nt = 24 (rows 96..99), wave-uniform branch
                float4 nv = *(const float4*)&row[96];
                acc[6][0][0] += nv.x * mv.x; acc[6][0][1] += nv.x * mv.y;
                acc[6][1][0] += nv.y * mv.x; acc[6][1][1] += nv.y * mv.y;
                acc[6][2][0] += nv.z * mv.x; acc[6][2][1] += nv.z * mv.y;
                acc[6][3][0] += nv.w * mv.x; acc[6][3][1] += nv.w * mv.y;
            }
        }
    }

    // ---- per-wave partial column max ----
    float px0 = -3.402823466e38f, px1 = -3.402823466e38f;
#pragma unroll
    for (int i = 0; i < 6; ++i)
#pragma unroll
        for (int j = 0; j < 4; ++j) {
            px0 = fmaxf(px0, acc[i][j][0]);
            px1 = fmaxf(px1, acc[i][j][1]);
        }
    if (wave == 0)
#pragma unroll
        for (int j = 0; j < 4; ++j) {
            px0 = fmaxf(px0, acc[6][j][0]);
            px1 = fmaxf(px1, acc[6][j][1]);
        }

    __syncthreads();  // all GEMM-phase LDS reads (incl. lane>=50 stray reads) done
    if (lane < 50)
        *(float2*)&sm[REDMAX + wave * NG + 2 * lane] = make_float2(px0, px1);
    __syncthreads();

    float2 q0 = *(const float2*)&sm[REDMAX + 0   + 2 * lane];
    float2 q1 = *(const float2*)&sm[REDMAX + 100 + 2 * lane];
    float2 q2 = *(const float2*)&sm[REDMAX + 200 + 2 * lane];
    float2 q3 = *(const float2*)&sm[REDMAX + 300 + 2 * lane];
    float gx0 = fmaxf(fmaxf(q0.x, q1.x), fmaxf(q2.x, q3.x));
    float gx1 = fmaxf(fmaxf(q0.y, q1.y), fmaxf(q2.y, q3.y));

    // ---- exp + per-wave partial column sum ----
    float ps0 = 0.f, ps1 = 0.f;
#pragma unroll
    for (int i = 0; i < 6; ++i)
#pragma unroll
        for (int j = 0; j < 4; ++j) {
            float e0 = __expf(acc[i][j][0] - gx0); acc[i][j][0] = e0; ps0 += e0;
            float e1 = __expf(acc[i][j][1] - gx1); acc[i][j][1] = e1; ps1 += e1;
        }
    if (wave == 0)
#pragma unroll
        for (int j = 0; j < 4; ++j) {
            float e0 = __expf(acc[6][j][0] - gx0); acc[6][j][0] = e0; ps0 += e0;
            float e1 = __expf(acc[6][j][1] - gx1); acc[6][j][1] = e1; ps1 += e1;
        }
    if (lane < 50)
        *(float2*)&sm[REDSUM + wave * NG + 2 * lane] = make_float2(ps0, ps1);
    __syncthreads();

    float2 u0 = *(const float2*)&sm[REDSUM + 0   + 2 * lane];
    float2 u1 = *(const float2*)&sm[REDSUM + 100 + 2 * lane];
    float2 u2 = *(const float2*)&sm[REDSUM + 200 + 2 * lane];
    float2 u3 = *(const float2*)&sm[REDSUM + 300 + 2 * lane];

    // ---- normalize + coalesced float2 stores ----
    if (lane < 50) {
        float r0 = 1.f / ((u0.x + u1.x) + (u2.x + u3.x));
        float r1 = 1.f / ((u0.y + u1.y) + (u2.y + u3.y));
#pragma unroll
        for (int i = 0; i < 6; ++i) {
            int nt = wave + 4 * i;
#pragma unroll
            for (int j = 0; j < 4; ++j) {
                int n = 4 * nt + j;
                *(float2*)&ob[n * NG + 2 * lane] =
                    make_float2(acc[i][j][0] * r0, acc[i][j][1] * r1);
            }
        }
        if (wave == 0)
#pragma unroll
            for (int j = 0; j < 4; ++j) {
                int n = 96 + j;
                *(float2*)&ob[n * NG + 2 * lane] =
                    make_float2(acc[6][j][0] * r0, acc[6][j][1] * r1);
            }
    }
}

extern "C" void kernel_launch(void* const* d_in, const int* in_sizes, int n_in,
                              void* d_out, int out_size, void* d_ws, size_t ws_size,
                              hipStream_t stream) {
    const float* x = (const float*)d_in[0];
    // d_in[1] (edge_index) and d_in[2] (graph_size) are dead in the reference math.
    float* out = (float*)d_out;
    const int B = in_sizes[0] / (NG * DD);   // 1024
    dim3 grid(B), block(256);
    hipLaunchKernelGGL(dotdec_kernel, grid, block, 0, stream, x, out);
}

// Round 2
// 156.980 us; speedup vs baseline: 1.2066x; 1.2066x over previous
//
#include <hip/hip_runtime.h>

#define NG 100    // graph size
#define DD 128    // feature dim
#define NPAD 112  // 7 * 16
#define LSTRIDE 136  // LDS row stride in bf16 elements (128 + 8 pad -> bank-balanced b128 reads)

typedef __attribute__((ext_vector_type(8))) short bf16x8;
typedef __attribute__((ext_vector_type(4))) float floatx4;

__device__ __forceinline__ unsigned int f2bf(float f) {
    // round-to-nearest-even fp32 -> bf16 (inputs are finite normals)
    unsigned int u = __float_as_uint(f);
    return (u + 0x7FFFu + ((u >> 16) & 1u)) >> 16;
}

// One block per graph. 4 waves. Wave w owns tile-col c0=w and c1=w+4 (wave 3: dup of c0).
// Tile grid: C[112][112] as 7x7 tiles of 16x16, K = 128 = 4 ksteps of 32.
// Lane owns output column m = c*16 + (lane&15); rows n = t2*16 + quad*4 + reg.
// Column softmax = in-register reduce over (t2, reg) + shfl_xor over quads (16, 32).
__global__ __launch_bounds__(256, 4)
void dotdec_mfma(const float* __restrict__ x, float* __restrict__ out) {
    __shared__ unsigned short xs[NPAD * LSTRIDE];  // 30,464 B
    const int t    = threadIdx.x;
    const int lane = t & 63;
    const int wave = t >> 6;
    const int quad = lane >> 4;
    const int lr   = lane & 15;
    const size_t b = blockIdx.x;
    const float* xb = x   + b * (size_t)(NG * DD);
    float*       ob = out + b * (size_t)(NG * NG);

    // ---- zero pad rows 100..111 (12 rows x 128 bf16 = 768 uints) ----
    for (int i = t; i < 12 * 64; i += 256) {
        int r = 100 + (i >> 6), cp = i & 63;
        *(unsigned int*)&xs[r * LSTRIDE + cp * 2] = 0u;
    }
    // ---- stage X fp32 -> bf16 into LDS, coalesced float4 loads ----
#pragma unroll
    for (int k = 0; k < 13; ++k) {
        int flat = t + 256 * k;          // float4 index: n*32 + g
        if (flat < NG * 32) {
            int n = flat >> 5, g = flat & 31;
            float4 v = ((const float4*)xb)[flat];
            unsigned int p0 = f2bf(v.x) | (f2bf(v.y) << 16);
            unsigned int p1 = f2bf(v.z) | (f2bf(v.w) << 16);
            *(uint2*)&xs[n * LSTRIDE + g * 4] = make_uint2(p0, p1);
        }
    }
    __syncthreads();

    // ---- MFMA GEMM: D = X * X^T for this wave's tile-columns ----
    const int c0 = wave;
    const int c1 = (wave < 3) ? wave + 4 : wave;   // wave3 duplicates c0 (stores skipped)
    floatx4 acc[2][7];
#pragma unroll
    for (int ci = 0; ci < 2; ++ci)
#pragma unroll
        for (int t2 = 0; t2 < 7; ++t2) acc[ci][t2] = (floatx4){0.f, 0.f, 0.f, 0.f};

#pragma unroll
    for (int k = 0; k < 4; ++k) {
        const int koff = k * 32 + quad * 8;
        bf16x8 b0 = *(const bf16x8*)&xs[(c0 * 16 + lr) * LSTRIDE + koff];
        bf16x8 b1 = *(const bf16x8*)&xs[(c1 * 16 + lr) * LSTRIDE + koff];
#pragma unroll
        for (int t2 = 0; t2 < 7; ++t2) {
            bf16x8 a = *(const bf16x8*)&xs[(t2 * 16 + lr) * LSTRIDE + koff];
            acc[0][t2] = __builtin_amdgcn_mfma_f32_16x16x32_bf16(a, b0, acc[0][t2], 0, 0, 0);
            acc[1][t2] = __builtin_amdgcn_mfma_f32_16x16x32_bf16(a, b1, acc[1][t2], 0, 0, 0);
        }
    }

    // ---- column max (rows n = t2*16 + quad*4 + i; t2==6 valid only for quad==0) ----
    float mx0 = -3.402823466e38f, mx1 = -3.402823466e38f;
#pragma unroll
    for (int t2 = 0; t2 < 6; ++t2)
#pragma unroll
        for (int i = 0; i < 4; ++i) {
            mx0 = fmaxf(mx0, acc[0][t2][i]);
            mx1 = fmaxf(mx1, acc[1][t2][i]);
        }
    if (quad == 0)
#pragma unroll
        for (int i = 0; i < 4; ++i) {
            mx0 = fmaxf(mx0, acc[0][6][i]);
            mx1 = fmaxf(mx1, acc[1][6][i]);
        }
    mx0 = fmaxf(mx0, __shfl_xor(mx0, 16, 64));
    mx0 = fmaxf(mx0, __shfl_xor(mx0, 32, 64));
    mx1 = fmaxf(mx1, __shfl_xor(mx1, 16, 64));
    mx1 = fmaxf(mx1, __shfl_xor(mx1, 32, 64));

    // ---- exp + column sum ----
    float s0 = 0.f, s1 = 0.f;
#pragma unroll
    for (int t2 = 0; t2 < 6; ++t2)
#pragma unroll
        for (int i = 0; i < 4; ++i) {
            float e0 = __expf(acc[0][t2][i] - mx0); acc[0][t2][i] = e0; s0 += e0;
            float e1 = __expf(acc[1][t2][i] - mx1); acc[1][t2][i] = e1; s1 += e1;
        }
    if (quad == 0)
#pragma unroll
        for (int i = 0; i < 4; ++i) {
            float e0 = __expf(acc[0][6][i] - mx0); acc[0][6][i] = e0; s0 += e0;
            float e1 = __expf(acc[1][6][i] - mx1); acc[1][6][i] = e1; s1 += e1;
        }
    s0 += __shfl_xor(s0, 16, 64); s0 += __shfl_xor(s0, 32, 64);
    s1 += __shfl_xor(s1, 16, 64); s1 += __shfl_xor(s1, 32, 64);
    const float r0 = 1.f / s0;
    const float r1 = 1.f / s1;

    // ---- normalize + store (m always < 100 for c0; c1==6 needs lr<4) ----
    const int m0 = c0 * 16 + lr;
    const int m1 = c1 * 16 + lr;
    const bool dual = (c1 != c0) && (m1 < NG);
#pragma unroll
    for (int t2 = 0; t2 < 6; ++t2)
#pragma unroll
        for (int i = 0; i < 4; ++i) {
            int n = t2 * 16 + quad * 4 + i;
            ob[n * NG + m0] = acc[0][t2][i] * r0;
            if (dual) ob[n * NG + m1] = acc[1][t2][i] * r1;
        }
    if (quad == 0)
#pragma unroll
        for (int i = 0; i < 4; ++i) {
            int n = 96 + i;
            ob[n * NG + m0] = acc[0][6][i] * r0;
            if (dual) ob[n * NG + m1] = acc[1][6][i] * r1;
        }
}

extern "C" void kernel_launch(void* const* d_in, const int* in_sizes, int n_in,
                              void* d_out, int out_size, void* d_ws, size_t ws_size,
                              hipStream_t stream) {
    const float* x = (const float*)d_in[0];
    // d_in[1] (edge_index) and d_in[2] (graph_size) are dead in the reference math.
    float* out = (float*)d_out;
    const int B = in_sizes[0] / (NG * DD);   // 1024
    hipLaunchKernelGGL(dotdec_mfma, dim3(B), dim3(256), 0, stream, x, out);
}

// Round 3
// 155.737 us; speedup vs baseline: 1.2162x; 1.0080x over previous
//
#include <hip/hip_runtime.h>

#define NG 100    // graph size
#define DD 128    // feature dim
#define NPAD 112  // 7 * 16
#define LSTRIDE 136  // LDS row stride in bf16 elements (128 + 8 pad -> balanced b128 reads)

typedef __attribute__((ext_vector_type(8))) short bf16x8;
typedef __attribute__((ext_vector_type(4))) float floatx4;

// One block per graph. 4 waves. Wave w owns tile-col c0=w and c1=w+4 (wave 3: dup of c0).
// Tile grid: C[112][112] as 7x7 tiles of 16x16, K = 128 = 4 ksteps of 32.
// GEMM: lane owns column m = c*16 + lr; rows n = t2*16 + quad*4 + reg.
// Column softmax = in-register reduce + shfl_xor(16,32); output transposed
// through LDS (reusing the staging buffer) for fully-coalesced float4 stores.
__global__ __launch_bounds__(256, 4)
void dotdec_mfma(const float* __restrict__ x, float* __restrict__ out) {
    __shared__ __align__(16) char smraw[NG * NG * 4];   // 40,000 B (>= 30,464 staging)
    unsigned short* xs = (unsigned short*)smraw;         // [NPAD][LSTRIDE] bf16
    float*          fo = (float*)smraw;                  // [NG][NG] fp32 (after compute)

    const int t    = threadIdx.x;
    const int lane = t & 63;
    const int wave = t >> 6;
    const int quad = lane >> 4;
    const int lr   = lane & 15;
    const size_t b = blockIdx.x;
    const float* xb = x   + b * (size_t)(NG * DD);
    float*       ob = out + b * (size_t)(NG * NG);

    // ---- zero pad rows 100..111 (data region only: 128 shorts/row), b128 ----
    if (t < 192) {
        int r = 100 + (t >> 4), c = t & 15;
        *(uint4*)&xs[r * LSTRIDE + c * 8] = make_uint4(0u, 0u, 0u, 0u);
    }
    // ---- stage X fp32 -> bf16 (truncate) into LDS: 32B/lane loads, b128 writes ----
#pragma unroll
    for (int k = 0; k < 7; ++k) {
        int p = t + 256 * k;             // pair-of-float4 index: n*16 + gp
        if (p < NG * 16) {
            int n = p >> 4, gp = p & 15;
            float4 v0 = ((const float4*)xb)[n * 32 + gp * 2];
            float4 v1 = ((const float4*)xb)[n * 32 + gp * 2 + 1];
            unsigned int u0 = (__float_as_uint(v0.x) >> 16) | (__float_as_uint(v0.y) & 0xffff0000u);
            unsigned int u1 = (__float_as_uint(v0.z) >> 16) | (__float_as_uint(v0.w) & 0xffff0000u);
            unsigned int u2 = (__float_as_uint(v1.x) >> 16) | (__float_as_uint(v1.y) & 0xffff0000u);
            unsigned int u3 = (__float_as_uint(v1.z) >> 16) | (__float_as_uint(v1.w) & 0xffff0000u);
            *(uint4*)&xs[n * LSTRIDE + gp * 8] = make_uint4(u0, u1, u2, u3);
        }
    }
    __syncthreads();

    // ---- MFMA GEMM: D = X * X^T for this wave's tile-columns ----
    const int c0 = wave;
    const int c1 = (wave < 3) ? wave + 4 : wave;   // wave3 duplicates c0 (stores skipped)
    floatx4 acc[2][7];
#pragma unroll
    for (int ci = 0; ci < 2; ++ci)
#pragma unroll
        for (int t2 = 0; t2 < 7; ++t2) acc[ci][t2] = (floatx4){0.f, 0.f, 0.f, 0.f};

#pragma unroll
    for (int k = 0; k < 4; ++k) {
        const int koff = k * 32 + quad * 8;
        bf16x8 b0 = *(const bf16x8*)&xs[(c0 * 16 + lr) * LSTRIDE + koff];
        bf16x8 b1 = *(const bf16x8*)&xs[(c1 * 16 + lr) * LSTRIDE + koff];
#pragma unroll
        for (int t2 = 0; t2 < 7; ++t2) {
            bf16x8 a = *(const bf16x8*)&xs[(t2 * 16 + lr) * LSTRIDE + koff];
            acc[0][t2] = __builtin_amdgcn_mfma_f32_16x16x32_bf16(a, b0, acc[0][t2], 0, 0, 0);
            acc[1][t2] = __builtin_amdgcn_mfma_f32_16x16x32_bf16(a, b1, acc[1][t2], 0, 0, 0);
        }
    }

    // ---- column max over valid rows (t2==6 valid only for quad==0) ----
    float mx0 = -3.402823466e38f, mx1 = -3.402823466e38f;
#pragma unroll
    for (int t2 = 0; t2 < 6; ++t2)
#pragma unroll
        for (int i = 0; i < 4; ++i) {
            mx0 = fmaxf(mx0, acc[0][t2][i]);
            mx1 = fmaxf(mx1, acc[1][t2][i]);
        }
    if (quad == 0)
#pragma unroll
        for (int i = 0; i < 4; ++i) {
            mx0 = fmaxf(mx0, acc[0][6][i]);
            mx1 = fmaxf(mx1, acc[1][6][i]);
        }
    mx0 = fmaxf(mx0, __shfl_xor(mx0, 16, 64));
    mx0 = fmaxf(mx0, __shfl_xor(mx0, 32, 64));
    mx1 = fmaxf(mx1, __shfl_xor(mx1, 16, 64));
    mx1 = fmaxf(mx1, __shfl_xor(mx1, 32, 64));

    // ---- exp + column sum ----
    float s0 = 0.f, s1 = 0.f;
#pragma unroll
    for (int t2 = 0; t2 < 6; ++t2)
#pragma unroll
        for (int i = 0; i < 4; ++i) {
            float e0 = __expf(acc[0][t2][i] - mx0); acc[0][t2][i] = e0; s0 += e0;
            float e1 = __expf(acc[1][t2][i] - mx1); acc[1][t2][i] = e1; s1 += e1;
        }
    if (quad == 0)
#pragma unroll
        for (int i = 0; i < 4; ++i) {
            float e0 = __expf(acc[0][6][i] - mx0); acc[0][6][i] = e0; s0 += e0;
            float e1 = __expf(acc[1][6][i] - mx1); acc[1][6][i] = e1; s1 += e1;
        }
    s0 += __shfl_xor(s0, 16, 64); s0 += __shfl_xor(s0, 32, 64);
    s1 += __shfl_xor(s1, 16, 64); s1 += __shfl_xor(s1, 32, 64);
    const float r0 = __builtin_amdgcn_rcpf(s0);   // outputs ~[0,1]; 1-ulp rcp is plenty
    const float r1 = __builtin_amdgcn_rcpf(s1);

    // ---- transpose through LDS (reuse staging buffer), then coalesced stores ----
    __syncthreads();   // all xs reads done before overwrite
    const int m0 = c0 * 16 + lr;                    // always < 64 < NG
    const int m1 = c1 * 16 + lr;
    const bool dual = (c1 != c0) && (m1 < NG);
#pragma unroll
    for (int t2 = 0; t2 < 6; ++t2)
#pragma unroll
        for (int i = 0; i < 4; ++i) {
            int n = t2 * 16 + quad * 4 + i;
            fo[n * NG + m0] = acc[0][t2][i] * r0;   // 2-way bank alias: free
            if (dual) fo[n * NG + m1] = acc[1][t2][i] * r1;
        }
    if (quad == 0)
#pragma unroll
        for (int i = 0; i < 4; ++i) {
            int n = 96 + i;
            fo[n * NG + m0] = acc[0][6][i] * r0;
            if (dual) fo[n * NG + m1] = acc[1][6][i] * r1;
        }
    __syncthreads();

#pragma unroll
    for (int k = 0; k < 10; ++k) {
        int f = t + 256 * k;                        // float4 index, < 2500
        if (f < (NG * NG) / 4) {
            float4 v = *(const float4*)&fo[f * 4];
            ((float4*)ob)[f] = v;                   // 1KB/wave/instr, fully coalesced
        }
    }
}

extern "C" void kernel_launch(void* const* d_in, const int* in_sizes, int n_in,
                              void* d_out, int out_size, void* d_ws, size_t ws_size,
                              hipStream_t stream) {
    const float* x = (const float*)d_in[0];
    // d_in[1] (edge_index) and d_in[2] (graph_size) are dead in the reference math.
    float* out = (float*)d_out;
    const int B = in_sizes[0] / (NG * DD);   // 1024
    hipLaunchKernelGGL(dotdec_mfma, dim3(B), dim3(256), 0, stream, x, out);
}